// Round 2
// baseline (1355.627 us; speedup 1.0000x reference)
//
#include <hip/hip_runtime.h>

#define BSZ   32768
#define INF   1024
#define UNITS 1024
#define NE    8

using bf16x8 = __attribute__((ext_vector_type(8))) __bf16;
using bf16x4 = __attribute__((ext_vector_type(4))) __bf16;
using f32x4  = __attribute__((ext_vector_type(4))) float;

// async global -> LDS, 16B per lane; LDS dest is wave-uniform base + lane*16
#define GLD_LDS16(gp, lp)                                                        \
  __builtin_amdgcn_global_load_lds((__attribute__((address_space(1))) void*)(gp),\
                                   (__attribute__((address_space(3))) void*)(lp),\
                                   16, 0, 0)

// ---------------------------------------------------------------------------
// Prepass: alpha (E, IN, UNITS) f32  ->  alphaT (E, UNITS, IN) bf16
// ---------------------------------------------------------------------------
__global__ __launch_bounds__(256) void transpose_cvt(const float* __restrict__ a,
                                                     __bf16* __restrict__ at) {
  __shared__ float tile[32][33];
  const int e  = blockIdx.z;
  const int u0 = blockIdx.x * 32;
  const int i0 = blockIdx.y * 32;
  const float* src = a  + (size_t)e * (INF * UNITS);
  __bf16*      dst = at + (size_t)e * (INF * UNITS);
  const int tx = threadIdx.x & 31, ty = threadIdx.x >> 5;  // 32 x 8
#pragma unroll
  for (int r = 0; r < 32; r += 8)
    tile[ty + r][tx] = src[(size_t)(i0 + ty + r) * UNITS + (u0 + tx)];
  __syncthreads();
#pragma unroll
  for (int r = 0; r < 32; r += 8)
    dst[(size_t)(u0 + ty + r) * INF + (i0 + tx)] = (__bf16)tile[tx][ty + r];
}

// ---------------------------------------------------------------------------
// Main GEMM: out[b,u] = sum_k Xs[b,k] * A'[k,u] + sum_e gate[b,e]*beta[e,u]
//   Xs[b, e*1024+i] = gate[b,e] * x[b,i]   (scaled on the fly during staging)
//   A'[k,u] read from alphaT bf16 via global_load_lds (B^T layout)
// Tile: BM=128, BN=128, BK=32; 256 threads = 4 waves, each 64x64 (4x4 frags)
// ---------------------------------------------------------------------------
__global__ __launch_bounds__(256, 3) void gemm_kernel(
    const float* __restrict__ x, const float* __restrict__ gate,
    const __bf16* __restrict__ aT, const float* __restrict__ beta,
    float* __restrict__ out) {
  // A padded to stride 40 (80B rows: only 2-way bank aliasing = free);
  // B unpadded [n][k] stride 32 (required: global_load_lds is lane-contiguous)
  __shared__ __align__(16) __bf16 lA[128 * 40];
  __shared__ __align__(16) __bf16 lB[128 * 32];

  const int t    = threadIdx.x;
  const int wave = t >> 6;
  const int lane = t & 63;
  const int bm   = blockIdx.y * 128;
  const int bn   = blockIdx.x * 128;

  // ---- A staging assignment: thread covers rows r0+32q, float4 chunk c4 ----
  const int r0 = t >> 3;  // 0..31
  const int c4 = t & 7;   // 0..7
  const float* xp[4];
  const float* gp[4];
#pragma unroll
  for (int q = 0; q < 4; ++q) {
    const int row = r0 + 32 * q;
    xp[q] = x + (size_t)(bm + row) * INF + c4 * 4;
    gp[q] = gate + (size_t)(bm + row) * NE;
  }

  // ---- B staging assignment (2 global_load_lds calls per wave) ----
  // NOTE: bn included — the B tile is the block's own 128-unit column band.
  const int nB0   = bn + wave * 32 + (lane >> 2);
  const int nB1   = nB0 + 16;
  const int koffB = (lane & 3) * 8;
  __bf16* lBdst0  = &lB[(wave * 32) * 32];       // wave-uniform
  __bf16* lBdst1  = &lB[(wave * 32 + 16) * 32];  // wave-uniform

  // ---- fragment addresses ----
  const int wm0 = (wave >> 1) * 64;
  const int wn0 = (wave & 1) * 64;
  const int fm  = lane & 15;         // m (A) / n (B) within 16-tile
  const int fk  = (lane >> 4) * 8;   // k offset within 32

  f32x4 acc[4][4] = {};
  float g[4];

  for (int kb = 0; kb < 256; ++kb) {
    const int e   = kb >> 5;
    const int kin = (kb & 31) * 32;
    if ((kb & 31) == 0) {  // expert boundary (uniform branch): reload gates
#pragma unroll
      for (int q = 0; q < 4; ++q) g[q] = gp[q][e];
    }
    // A global loads (fp32)
    f32x4 va[4];
#pragma unroll
    for (int q = 0; q < 4; ++q) va[q] = *(const f32x4*)(xp[q] + kin);
    // B async direct-to-LDS loads (bf16, already transposed)
    const __bf16* bsrc = aT + ((size_t)e << 20) + kin + koffB;
    GLD_LDS16(bsrc + (size_t)nB0 * INF, lBdst0);
    GLD_LDS16(bsrc + (size_t)nB1 * INF, lBdst1);
    // A: scale by gate, convert to bf16, write to LDS
#pragma unroll
    for (int q = 0; q < 4; ++q) {
      bf16x4 h;
      h.x = (__bf16)(va[q].x * g[q]);
      h.y = (__bf16)(va[q].y * g[q]);
      h.z = (__bf16)(va[q].z * g[q]);
      h.w = (__bf16)(va[q].w * g[q]);
      *(bf16x4*)&lA[(r0 + 32 * q) * 40 + c4 * 4] = h;
    }
    __syncthreads();

    bf16x8 af[4], bfr[4];
#pragma unroll
    for (int i = 0; i < 4; ++i)
      af[i] = *(const bf16x8*)&lA[(wm0 + i * 16 + fm) * 40 + fk];
#pragma unroll
    for (int j = 0; j < 4; ++j)
      bfr[j] = *(const bf16x8*)&lB[(wn0 + j * 16 + fm) * 32 + fk];
#pragma unroll
    for (int i = 0; i < 4; ++i)
#pragma unroll
      for (int j = 0; j < 4; ++j)
        acc[i][j] =
            __builtin_amdgcn_mfma_f32_16x16x32_bf16(af[i], bfr[j], acc[i][j], 0, 0, 0);
    __syncthreads();
  }

  // ---- epilogue: add rank-8 bias  sum_e gate[b,e]*beta[e,u]  and store ----
  float bcol[4][NE];
#pragma unroll
  for (int j = 0; j < 4; ++j) {
    const int u = bn + wn0 + j * 16 + fm;
#pragma unroll
    for (int e2 = 0; e2 < NE; ++e2) bcol[j][e2] = beta[e2 * UNITS + u];
  }
#pragma unroll
  for (int i = 0; i < 4; ++i) {
#pragma unroll
    for (int r = 0; r < 4; ++r) {
      const int b = bm + wm0 + i * 16 + (lane >> 4) * 4 + r;
      const float* gr = gate + (size_t)b * NE;
      float g8[NE];
#pragma unroll
      for (int e2 = 0; e2 < NE; ++e2) g8[e2] = gr[e2];
#pragma unroll
      for (int j = 0; j < 4; ++j) {
        float bias = 0.f;
#pragma unroll
        for (int e2 = 0; e2 < NE; ++e2) bias += g8[e2] * bcol[j][e2];
        const int u = bn + wn0 + j * 16 + fm;
        out[(size_t)b * UNITS + u] = acc[i][j][r] + bias;
      }
    }
  }
}

// ---------------------------------------------------------------------------
extern "C" void kernel_launch(void* const* d_in, const int* in_sizes, int n_in,
                              void* d_out, int out_size, void* d_ws, size_t ws_size,
                              hipStream_t stream) {
  const float* x     = (const float*)d_in[0];  // (B, IN)
  const float* gate  = (const float*)d_in[1];  // (B, E)
  const float* alpha = (const float*)d_in[2];  // (E, IN, UNITS)
  const float* beta  = (const float*)d_in[3];  // (E, UNITS)
  float* out         = (float*)d_out;          // (B, UNITS)
  __bf16* aT         = (__bf16*)d_ws;          // 16 MiB: (E, UNITS, IN) bf16

  transpose_cvt<<<dim3(UNITS / 32, INF / 32, NE), 256, 0, stream>>>(alpha, aT);
  gemm_kernel<<<dim3(UNITS / 128, BSZ / 128), 256, 0, stream>>>(x, gate, aT, beta, out);
}

// Round 3
// 920.223 us; speedup vs baseline: 1.4732x; 1.4732x over previous
//
#include <hip/hip_runtime.h>

#define BSZ   32768
#define INF   1024
#define UNITS 1024
#define NE    8

using bf16x8 = __attribute__((ext_vector_type(8))) __bf16;
using bf16x4 = __attribute__((ext_vector_type(4))) __bf16;
using f32x4  = __attribute__((ext_vector_type(4))) float;

// async global -> LDS, 16B per lane; LDS dest is wave-uniform base + lane*16
#define GLD_LDS16(gp, lp)                                                        \
  __builtin_amdgcn_global_load_lds((__attribute__((address_space(1))) void*)(gp),\
                                   (__attribute__((address_space(3))) void*)(lp),\
                                   16, 0, 0)

// ---------------------------------------------------------------------------
// Prepass 1: alpha (E, IN, UNITS) f32  ->  alphaT (E, UNITS, IN) bf16
// ---------------------------------------------------------------------------
__global__ __launch_bounds__(256) void transpose_cvt(const float* __restrict__ a,
                                                     __bf16* __restrict__ at) {
  __shared__ float tile[32][33];
  const int e  = blockIdx.z;
  const int u0 = blockIdx.x * 32;
  const int i0 = blockIdx.y * 32;
  const float* src = a  + (size_t)e * (INF * UNITS);
  __bf16*      dst = at + (size_t)e * (INF * UNITS);
  const int tx = threadIdx.x & 31, ty = threadIdx.x >> 5;  // 32 x 8
#pragma unroll
  for (int r = 0; r < 32; r += 8)
    tile[ty + r][tx] = src[(size_t)(i0 + ty + r) * UNITS + (u0 + tx)];
  __syncthreads();
#pragma unroll
  for (int r = 0; r < 32; r += 8)
    dst[(size_t)(u0 + ty + r) * INF + (i0 + tx)] = (__bf16)tile[tx][ty + r];
}

// ---------------------------------------------------------------------------
// Prepass 2: x (B, IN) f32 -> xb (B, IN) bf16   (8 elements / thread)
// ---------------------------------------------------------------------------
__global__ __launch_bounds__(256) void cvt_x(const float* __restrict__ x,
                                             __bf16* __restrict__ xb) {
  const size_t i = ((size_t)blockIdx.x * 256 + threadIdx.x) * 8;
  f32x4 a = *(const f32x4*)(x + i);
  f32x4 b = *(const f32x4*)(x + i + 4);
  bf16x8 h;
  h[0] = (__bf16)a.x; h[1] = (__bf16)a.y; h[2] = (__bf16)a.z; h[3] = (__bf16)a.w;
  h[4] = (__bf16)b.x; h[5] = (__bf16)b.y; h[6] = (__bf16)b.z; h[7] = (__bf16)b.w;
  *(bf16x8*)(xb + i) = h;
}

// ---------------------------------------------------------------------------
// GEMM with Horner gate folding:
//   for e outer: acc accumulates P_e = x @ alpha_e over 32 k-chunks;
//   at boundary e-1 -> e:  acc *= g[b,e-1] / g[b,e]
//   final: out = g[b,7] * acc + sum_e g[b,e]*beta[e,u]
// Invariant after expert e: acc = (sum_{e'<=e} g_e' P_e') / g_e  (exact in R)
// Tile: BM=128, BN=128, BK=32; 256 thr = 4 waves x (64x64); A,B both via
// global_load_lds into unpadded [row][k] stride-32 LDS (m97 layout).
// ---------------------------------------------------------------------------
__global__ __launch_bounds__(256, 3) void gemm_kernel(
    const __bf16* __restrict__ xb, const float* __restrict__ gate,
    const __bf16* __restrict__ aT, const float* __restrict__ beta,
    float* __restrict__ out) {
  __shared__ __align__(16) __bf16 lA[128 * 32];
  __shared__ __align__(16) __bf16 lB[128 * 32];
  __shared__ float lG[128 * NE];  // gates for this block's 128 rows

  const int t    = threadIdx.x;
  const int wave = t >> 6;
  const int lane = t & 63;
  const int bm   = blockIdx.y * 128;
  const int bn   = blockIdx.x * 128;

  // stage gates once (coalesced float4: 256 thr x 4 = 1024 floats)
  *(f32x4*)&lG[t * 4] = *(const f32x4*)&gate[(size_t)bm * NE + t * 4];

  // ---- staging addressing (identical pattern for A and B) ----
  const int rowS  = wave * 32 + (lane >> 2);  // 0..127 over 2 calls
  const int koff  = (lane & 3) * 8;           // bf16 elems
  const __bf16* xsrc0 = xb + (size_t)(bm + rowS) * INF + koff;
  const __bf16* xsrc1 = xsrc0 + (size_t)16 * INF;
  const __bf16* bsrc0 = aT + (size_t)(bn + rowS) * INF + koff;
  const __bf16* bsrc1 = bsrc0 + (size_t)16 * INF;
  __bf16* lAdst0 = &lA[(wave * 32) * 32];
  __bf16* lAdst1 = &lA[(wave * 32 + 16) * 32];
  __bf16* lBdst0 = &lB[(wave * 32) * 32];
  __bf16* lBdst1 = &lB[(wave * 32 + 16) * 32];

  // ---- fragment addressing ----
  const int wm0 = (wave >> 1) * 64;
  const int wn0 = (wave & 1) * 64;
  const int fm  = lane & 15;
  const int fq  = (lane >> 4) * 4;   // C/D row quad base
  const int fk  = (lane >> 4) * 8;   // A/B k offset

  f32x4 acc[4][4] = {};
  float gcur[4][4];  // current expert's gate for this lane's 16 rows

  __syncthreads();  // lG visible

  for (int kb = 0; kb < 256; ++kb) {
    const int e   = kb >> 5;
    const int kin = (kb & 31) * 32;

    if ((kb & 31) == 0) {  // expert boundary (wave-uniform)
#pragma unroll
      for (int i = 0; i < 4; ++i)
#pragma unroll
        for (int r = 0; r < 4; ++r) {
          const int row = wm0 + i * 16 + fq + r;
          const float gn = lG[row * NE + e];
          if (kb) {
            const float ratio = gcur[i][r] / gn;
#pragma unroll
            for (int j = 0; j < 4; ++j) acc[i][j][r] *= ratio;
          }
          gcur[i][r] = gn;
        }
    }

    // async staging: A (x chunk) + B (alphaT chunk), 4 calls/wave, 16B/lane
    GLD_LDS16(xsrc0 + kin, lAdst0);
    GLD_LDS16(xsrc1 + kin, lAdst1);
    const size_t eoff = (size_t)e << 20;  // e * UNITS * INF
    GLD_LDS16(bsrc0 + eoff + kin, lBdst0);
    GLD_LDS16(bsrc1 + eoff + kin, lBdst1);
    __syncthreads();  // drains vmcnt (GLD) + makes LDS visible

    bf16x8 af[4], bfr[4];
#pragma unroll
    for (int i = 0; i < 4; ++i)
      af[i] = *(const bf16x8*)&lA[(wm0 + i * 16 + fm) * 32 + fk];
#pragma unroll
    for (int j = 0; j < 4; ++j)
      bfr[j] = *(const bf16x8*)&lB[(wn0 + j * 16 + fm) * 32 + fk];
#pragma unroll
    for (int i = 0; i < 4; ++i)
#pragma unroll
      for (int j = 0; j < 4; ++j)
        acc[i][j] =
            __builtin_amdgcn_mfma_f32_16x16x32_bf16(af[i], bfr[j], acc[i][j], 0, 0, 0);
    __syncthreads();
  }

  // ---- epilogue: out = g7*acc + sum_e gate[b,e]*beta[e,u] ----
  float bcol[4][NE];
#pragma unroll
  for (int j = 0; j < 4; ++j) {
    const int u = bn + wn0 + j * 16 + fm;
#pragma unroll
    for (int e2 = 0; e2 < NE; ++e2) bcol[j][e2] = beta[e2 * UNITS + u];
  }
#pragma unroll
  for (int i = 0; i < 4; ++i) {
#pragma unroll
    for (int r = 0; r < 4; ++r) {
      const int row = wm0 + i * 16 + fq + r;
      const int b   = bm + row;
      float g8[NE];
#pragma unroll
      for (int e2 = 0; e2 < NE; ++e2) g8[e2] = lG[row * NE + e2];
#pragma unroll
      for (int j = 0; j < 4; ++j) {
        float bias = 0.f;
#pragma unroll
        for (int e2 = 0; e2 < NE; ++e2) bias += g8[e2] * bcol[j][e2];
        const int u = bn + wn0 + j * 16 + fm;
        out[(size_t)b * UNITS + u] = gcur[i][r] * acc[i][j][r] + bias;
      }
    }
  }
}

// ---------------------------------------------------------------------------
extern "C" void kernel_launch(void* const* d_in, const int* in_sizes, int n_in,
                              void* d_out, int out_size, void* d_ws, size_t ws_size,
                              hipStream_t stream) {
  const float* x     = (const float*)d_in[0];  // (B, IN)
  const float* gate  = (const float*)d_in[1];  // (B, E)
  const float* alpha = (const float*)d_in[2];  // (E, IN, UNITS)
  const float* beta  = (const float*)d_in[3];  // (E, UNITS)
  float* out         = (float*)d_out;          // (B, UNITS)
  __bf16* aT = (__bf16*)d_ws;                           // 16 MiB
  __bf16* xbp = (__bf16*)((char*)d_ws + (size_t)16 * 1024 * 1024);  // 64 MiB

  transpose_cvt<<<dim3(UNITS / 32, INF / 32, NE), 256, 0, stream>>>(alpha, aT);
  cvt_x<<<dim3(BSZ * INF / (256 * 8)), 256, 0, stream>>>(x, xbp);
  gemm_kernel<<<dim3(UNITS / 128, BSZ / 128), 256, 0, stream>>>(xbp, gate, aT, beta, out);
}